// Round 1
// baseline (27.452 us; speedup 1.0000x reference)
//
#include <hip/hip_runtime.h>
#include <cstdint>
#include <cstddef>

#define BATCH 4
#define NTOK  4096
#define CCH   256
#define IMH   512
#define IMW   512
#define PMAXV 124
#define NKEYS (PMAXV * PMAXV)   // 15376

// ---------------------------------------------------------------------------
// Kernel 1: init first-occurrence table to INT_MAX (must run every call; the
// harness does not re-poison d_ws between replays).
// ---------------------------------------------------------------------------
__global__ void init_table_k(int* __restrict__ table, int n) {
    int t = blockIdx.x * blockDim.x + threadIdx.x;
    if (t < n) table[t] = 0x7FFFFFFF;
}

// ---------------------------------------------------------------------------
// Kernel 2: for each (b, j) record the first j (atomicMin) whose shuffled
// position hashes to key = p0*124 + p1. Since pos_shuffled is an exact
// permutation of pos_org, argmin(L1 dist) == first exact match == table hit.
// ---------------------------------------------------------------------------
__global__ void build_table_k(const int* __restrict__ ps, int* __restrict__ table) {
    int t = blockIdx.x * blockDim.x + threadIdx.x;   // over BATCH*NTOK
    if (t >= BATCH * NTOK) return;
    int b = t / NTOK;
    int j = t - b * NTOK;
    int p0 = ps[2 * t];
    int p1 = ps[2 * t + 1];
    atomicMin(&table[b * NKEYS + p0 * PMAXV + p1], j);
}

// ---------------------------------------------------------------------------
// Kernel 3: gather feat rows. One float4 per thread; 64 consecutive threads
// cover one C=256 row (1 KiB, fully coalesced). Table read broadcasts.
// ---------------------------------------------------------------------------
__global__ void gather_feat_k(const float4* __restrict__ feat,
                              const int* __restrict__ po,
                              const int* __restrict__ table,
                              float4* __restrict__ out) {
    int t  = blockIdx.x * blockDim.x + threadIdx.x;  // BATCH*NTOK*64 threads
    int c4 = t & 63;
    int bi = t >> 6;                                  // (b, i) flat
    int b  = bi / NTOK;
    int p0 = po[2 * bi];
    int p1 = po[2 * bi + 1];
    int idx = table[b * NKEYS + p0 * PMAXV + p1];
    out[t] = feat[((size_t)(b * NTOK + idx)) * 64 + c4];
}

// ---------------------------------------------------------------------------
// Kernel 4: patch edge-energy sum. 16 threads per (b,i), one per patch pixel.
// em is recomputed on the fly via the 5-point stencil (never materialized):
//   em[r,c] = sum_ch [ |v - up| + |down - v| + |v - left| + |right - v| ]
// with edges clipped at the image border. Patch max coord = 123*4+3 = 495,
// so bottom/right guards never fire, but keep them for generality.
// Reduce the 16 values with shfl_xor inside each 16-lane group.
// ---------------------------------------------------------------------------
__global__ void dis_k(const float* __restrict__ im,
                      const int* __restrict__ po,
                      float* __restrict__ dis) {
    int t = blockIdx.x * blockDim.x + threadIdx.x;   // BATCH*NTOK*16 threads
    int k  = t & 15;
    int bi = t >> 4;
    int b  = bi / NTOK;
    int p0 = po[2 * bi];
    int p1 = po[2 * bi + 1];
    int col = p0 * 4 + (k >> 2);   // x = pp[...,0] indexes columns
    int row = p1 * 4 + (k & 3);    // y = pp[...,1] indexes rows

    float s = 0.f;
#pragma unroll
    for (int ch = 0; ch < 3; ++ch) {
        const float* base = im + (((size_t)(b * 3 + ch)) * IMH + row) * IMW + col;
        float v = base[0];
        if (row > 0)        s += fabsf(v - base[-IMW]);
        if (row < IMH - 1)  s += fabsf(base[IMW] - v);
        if (col > 0)        s += fabsf(v - base[-1]);
        if (col < IMW - 1)  s += fabsf(base[1] - v);
    }
    // reduce 16 patch-pixel values within each aligned 16-lane group
    s += __shfl_xor(s, 1, 64);
    s += __shfl_xor(s, 2, 64);
    s += __shfl_xor(s, 4, 64);
    s += __shfl_xor(s, 8, 64);
    if (k == 0) dis[bi] = s;
}

// ---------------------------------------------------------------------------
// Fallback (only if ws_size < table size, which should not happen): one block
// per (b,i); full scan for first match, then fused coalesced feat-row copy.
// ---------------------------------------------------------------------------
__global__ void match_gather_fb_k(const float* __restrict__ feat,
                                  const int* __restrict__ po,
                                  const int* __restrict__ ps,
                                  float* __restrict__ out) {
    int bi = blockIdx.x;            // BATCH*NTOK blocks
    int b  = bi / NTOK;
    int tid = threadIdx.x;          // 256 threads
    int p0 = po[2 * bi];
    int p1 = po[2 * bi + 1];
    __shared__ int s_idx;
    if (tid == 0) s_idx = NTOK;
    __syncthreads();
    const int* psb = ps + (size_t)b * NTOK * 2;
    for (int j = tid; j < NTOK; j += 256) {
        if (psb[2 * j] == p0 && psb[2 * j + 1] == p1) atomicMin(&s_idx, j);
    }
    __syncthreads();
    int idx = s_idx;
    out[(size_t)bi * CCH + tid] = feat[((size_t)b * NTOK + idx) * CCH + tid];
}

extern "C" void kernel_launch(void* const* d_in, const int* in_sizes, int n_in,
                              void* d_out, int out_size, void* d_ws, size_t ws_size,
                              hipStream_t stream) {
    const float* feat         = (const float*)d_in[0];
    const float* images       = (const float*)d_in[1];
    const int*   pos_org      = (const int*)d_in[2];
    const int*   pos_shuffled = (const int*)d_in[3];
    // d_in[4] = patch_size (4), d_in[5] = min_patch_size (4): fixed constants.

    float* out_feat = (float*)d_out;
    float* out_dis  = out_feat + (size_t)BATCH * NTOK * CCH;

    const size_t table_bytes = (size_t)BATCH * NKEYS * sizeof(int);

    if (ws_size >= table_bytes) {
        int* table = (int*)d_ws;
        {
            int n = BATCH * NKEYS;
            init_table_k<<<(n + 255) / 256, 256, 0, stream>>>(table, n);
        }
        build_table_k<<<(BATCH * NTOK + 255) / 256, 256, 0, stream>>>(pos_shuffled, table);
        gather_feat_k<<<(BATCH * NTOK * 64) / 256, 256, 0, stream>>>(
            (const float4*)feat, pos_org, table, (float4*)out_feat);
    } else {
        match_gather_fb_k<<<BATCH * NTOK, 256, 0, stream>>>(feat, pos_org, pos_shuffled, out_feat);
    }

    dis_k<<<(BATCH * NTOK * 16) / 256, 256, 0, stream>>>(images, pos_org, out_dis);
}

// Round 2
// 25.957 us; speedup vs baseline: 1.0576x; 1.0576x over previous
//
#include <hip/hip_runtime.h>
#include <cstdint>
#include <cstddef>

#define BATCH 4
#define NTOK  4096
#define CCH   256
#define IMH   512
#define IMW   512
#define PMAXV 124
#define NKEYS (PMAXV * PMAXV)   // 15376

// ---------------------------------------------------------------------------
// K1: match via per-block LDS hash table (first-occurrence index).
// Since pos_shuffled is an exact permutation of pos_org, argmin(L1) == first
// exact coordinate match. Table keyed by p0*124+p1; atomicMin keeps first j.
// Grid: 16 blocks = 4 batches x 4 query-quarters. Each block rebuilds the
// (cheap) table for its batch, then answers 1024 queries.
// ---------------------------------------------------------------------------
__global__ __launch_bounds__(256) void match_k(const int2* __restrict__ ps,
                                               const int2* __restrict__ po,
                                               int* __restrict__ idx_out) {
    __shared__ int tbl[NKEYS];   // 61.5 KB LDS
    const int b   = blockIdx.x >> 2;
    const int q   = blockIdx.x & 3;
    const int tid = threadIdx.x;

    for (int k = tid; k < NKEYS; k += 256) tbl[k] = 0x7FFFFFFF;
    __syncthreads();

    const int2* psb = ps + (size_t)b * NTOK;
    for (int j = tid; j < NTOK; j += 256) {
        int2 p = psb[j];
        atomicMin(&tbl[p.x * PMAXV + p.y], j);
    }
    __syncthreads();

    const int2* pob = po + (size_t)b * NTOK;
    const int i0 = q * (NTOK / 4);
    for (int i = i0 + tid; i < i0 + NTOK / 4; i += 256) {
        int2 p = pob[i];
        idx_out[b * NTOK + i] = tbl[p.x * PMAXV + p.y];
    }
}

// ---------------------------------------------------------------------------
// K2: fused feat gather + patch edge-energy sum.
// One 64-lane wave per (b,i) row:
//   - every lane copies one float4 of the C=256 feat row (1 KiB coalesced)
//   - lanes 0..47 each handle one (channel, patch-pixel): recompute the
//     em stencil on the fly (5 loads, 4 abs-diffs); full-wave shfl reduce.
// Patch max coord = 123*4+3 = 495 < 511, so only top/left guards can fire.
// ---------------------------------------------------------------------------
__global__ __launch_bounds__(256) void gather_dis_k(const float4* __restrict__ feat,
                                                    const float* __restrict__ im,
                                                    const int2* __restrict__ po,
                                                    const int* __restrict__ idx_ws,
                                                    float4* __restrict__ out_feat,
                                                    float* __restrict__ out_dis) {
    const int tid  = threadIdx.x;
    const int lane = tid & 63;
    const int row  = blockIdx.x * 4 + (tid >> 6);   // flat (b,i), 0..16383
    const int b    = row >> 12;                     // row / NTOK

    // --- gather (all 64 lanes) ---
    const int idx = idx_ws[row];                    // same addr per wave: broadcast
    out_feat[(size_t)row * 64 + lane] = feat[((size_t)(b * NTOK + idx)) * 64 + lane];

    // --- dis (lanes 0..47: ch = lane>>4, pixel = lane&15) ---
    float s = 0.f;
    if (lane < 48) {
        int2 p = po[row];
        const int ch  = lane >> 4;
        const int k   = lane & 15;
        const int col = p.x * 4 + (k >> 2);         // x indexes columns
        const int r   = p.y * 4 + (k & 3);          // y indexes rows
        const float* base = im + (((size_t)(b * 3 + ch)) * IMH + r) * IMW + col;
        const float v = base[0];
        if (r > 0)         s += fabsf(v - base[-IMW]);
        if (r < IMH - 1)   s += fabsf(base[IMW] - v);
        if (col > 0)       s += fabsf(v - base[-1]);
        if (col < IMW - 1) s += fabsf(base[1] - v);
    }
    s += __shfl_xor(s, 1,  64);
    s += __shfl_xor(s, 2,  64);
    s += __shfl_xor(s, 4,  64);
    s += __shfl_xor(s, 8,  64);
    s += __shfl_xor(s, 16, 64);
    s += __shfl_xor(s, 32, 64);
    if (lane == 0) out_dis[row] = s;
}

// ---------------------------------------------------------------------------
// Fallback (ws too small; should never trigger): one block per (b,i), full
// scan for first match + fused coalesced feat-row copy; separate dis kernel.
// ---------------------------------------------------------------------------
__global__ void match_gather_fb_k(const float* __restrict__ feat,
                                  const int* __restrict__ po,
                                  const int* __restrict__ ps,
                                  float* __restrict__ out) {
    int bi = blockIdx.x;
    int b  = bi / NTOK;
    int tid = threadIdx.x;
    int p0 = po[2 * bi];
    int p1 = po[2 * bi + 1];
    __shared__ int s_idx;
    if (tid == 0) s_idx = NTOK;
    __syncthreads();
    const int* psb = ps + (size_t)b * NTOK * 2;
    for (int j = tid; j < NTOK; j += 256) {
        if (psb[2 * j] == p0 && psb[2 * j + 1] == p1) atomicMin(&s_idx, j);
    }
    __syncthreads();
    out[(size_t)bi * CCH + tid] = feat[((size_t)b * NTOK + s_idx) * CCH + tid];
}

__global__ void dis_fb_k(const float* __restrict__ im,
                         const int* __restrict__ po,
                         float* __restrict__ dis) {
    int t = blockIdx.x * blockDim.x + threadIdx.x;
    int k  = t & 15;
    int bi = t >> 4;
    int b  = bi / NTOK;
    int p0 = po[2 * bi];
    int p1 = po[2 * bi + 1];
    int col = p0 * 4 + (k >> 2);
    int row = p1 * 4 + (k & 3);
    float s = 0.f;
#pragma unroll
    for (int ch = 0; ch < 3; ++ch) {
        const float* base = im + (((size_t)(b * 3 + ch)) * IMH + row) * IMW + col;
        float v = base[0];
        if (row > 0)        s += fabsf(v - base[-IMW]);
        if (row < IMH - 1)  s += fabsf(base[IMW] - v);
        if (col > 0)        s += fabsf(v - base[-1]);
        if (col < IMW - 1)  s += fabsf(base[1] - v);
    }
    s += __shfl_xor(s, 1, 64);
    s += __shfl_xor(s, 2, 64);
    s += __shfl_xor(s, 4, 64);
    s += __shfl_xor(s, 8, 64);
    if (k == 0) dis[bi] = s;
}

extern "C" void kernel_launch(void* const* d_in, const int* in_sizes, int n_in,
                              void* d_out, int out_size, void* d_ws, size_t ws_size,
                              hipStream_t stream) {
    const float* feat         = (const float*)d_in[0];
    const float* images       = (const float*)d_in[1];
    const int*   pos_org      = (const int*)d_in[2];
    const int*   pos_shuffled = (const int*)d_in[3];

    float* out_feat = (float*)d_out;
    float* out_dis  = out_feat + (size_t)BATCH * NTOK * CCH;

    const size_t idx_bytes = (size_t)BATCH * NTOK * sizeof(int);

    if (ws_size >= idx_bytes) {
        int* idx_ws = (int*)d_ws;
        match_k<<<16, 256, 0, stream>>>((const int2*)pos_shuffled,
                                        (const int2*)pos_org, idx_ws);
        gather_dis_k<<<BATCH * NTOK / 4, 256, 0, stream>>>(
            (const float4*)feat, images, (const int2*)pos_org, idx_ws,
            (float4*)out_feat, out_dis);
    } else {
        match_gather_fb_k<<<BATCH * NTOK, 256, 0, stream>>>(feat, pos_org, pos_shuffled, out_feat);
        dis_fb_k<<<(BATCH * NTOK * 16) / 256, 256, 0, stream>>>(images, pos_org, out_dis);
    }
}